// Round 2
// baseline (9384.718 us; speedup 1.0000x reference)
//
#include <hip/hip_runtime.h>
#include <cstdint>

// Problem: B=32, S=1024, D=1024 ContractiveSequenceMixer
//   gates = sigmoid(x @ Wg^T + bg); pin = x @ Wi^T + bi   (precomputable)
//   scan t: mix = h @ Ws^T + bs + pin_t ; h = g_t*mix + (1-g_t)*h ; emit h
// out = [emitted (B,S,D) fp32 | final_state (B,D) fp32]
//
// R2 change: recurrence cross-WG exchange via agent-scope relaxed atomics
// (L2-bypassing, performed at L3) + per-step counter sync. NO cache fences
// (R1's buffer_wbl2/buffer_inv per step per WG was ~98% stall).

#define BATCH 32
#define SEQ   1024
#define DIM   1024
static const size_t BSD = (size_t)BATCH * SEQ * DIM; // 33554432

typedef short  s16x8 __attribute__((ext_vector_type(8)));
typedef unsigned short u16x4 __attribute__((ext_vector_type(4)));
typedef float  f32x4 __attribute__((ext_vector_type(4)));

__device__ __forceinline__ unsigned short f2bf(float f) {
  union { float f; unsigned int u; } v; v.f = f;
  unsigned int r = v.u + 0x7fffu + ((v.u >> 16) & 1u);  // RNE
  return (unsigned short)(r >> 16);
}
__device__ __forceinline__ float bf2f(unsigned short h) {
  union { unsigned int u; float f; } v; v.u = ((unsigned int)h) << 16; return v.f;
}

__device__ __forceinline__ void gload_lds16(const void* g, void* l) {
  __builtin_amdgcn_global_load_lds(
      (const __attribute__((address_space(1))) void*)g,
      (__attribute__((address_space(3))) void*)l, 16, 0, 0);
}

// ---------------- prep kernels ----------------
__global__ void split_x_kernel(const float* __restrict__ x,
                               unsigned short* __restrict__ xh,
                               unsigned short* __restrict__ xl, long n4) {
  long i = (long)blockIdx.x * blockDim.x + threadIdx.x;
  const long stride = (long)gridDim.x * blockDim.x;
  for (; i < n4; i += stride) {
    f32x4 v = *(const f32x4*)&x[i * 4];
    u16x4 vh, vl;
#pragma unroll
    for (int j = 0; j < 4; ++j) {
      unsigned short hb = f2bf(v[j]);
      vh[j] = hb; vl[j] = f2bf(v[j] - bf2f(hb));
    }
    *(u16x4*)&xh[i * 4] = vh;
    *(u16x4*)&xl[i * 4] = vl;
  }
}

__global__ void split_w_kernel(const float* __restrict__ Wg,
                               const float* __restrict__ Wi,
                               unsigned short* __restrict__ wh,
                               unsigned short* __restrict__ wl) {
  long i = (long)blockIdx.x * blockDim.x + threadIdx.x; // 524288 float4 groups
  if (i >= (long)(2048 * 1024 / 4)) return;
  long flat = i * 4;
  int row = (int)(flat >> 10);
  int col = (int)(flat & 1023);
  const float* src = (row < 1024) ? &Wg[(size_t)row * 1024 + col]
                                  : &Wi[(size_t)(row - 1024) * 1024 + col];
  f32x4 v = *(const f32x4*)src;
  u16x4 vh, vl;
#pragma unroll
  for (int j = 0; j < 4; ++j) {
    unsigned short hb = f2bf(v[j]);
    vh[j] = hb; vl[j] = f2bf(v[j] - bf2f(hb));
  }
  *(u16x4*)&wh[flat] = vh;
  *(u16x4*)&wl[flat] = vl;
}

// h buffers are u64-typed (8192 u64 per parity). cnt[0]=32 (h_0 published).
__global__ void init_kernel(unsigned long long* h_hi, unsigned long long* h_lo,
                            int* cnt) {
  int i = blockIdx.x * blockDim.x + threadIdx.x;  // 16384 launched
  if (i < 16384) { h_hi[i] = 0ull; h_lo[i] = 0ull; }
  if (i < 1025) cnt[i] = (i == 0) ? 32 : 0;
}

// ---------------- fused G/P GEMM (split-bf16, 3-term) ----------------
// out[r][c] = sum_k x[r][k]*Wcat[c][k], r<32768, c<2048, K=1024
// c<1024 -> G = sigmoid(out+bg) ; c>=1024 -> P = out+bi  (P lives in d_out)
__global__ __launch_bounds__(256) void gemm_gp_kernel(
    const unsigned short* __restrict__ xh, const unsigned short* __restrict__ xl,
    const unsigned short* __restrict__ wh, const unsigned short* __restrict__ wl,
    const float* __restrict__ bg, const float* __restrict__ bi,
    float* __restrict__ G, float* __restrict__ P) {
  __shared__ unsigned short sAh[128 * 32], sAl[128 * 32], sBh[128 * 32], sBl[128 * 32];
  const int tid = threadIdx.x;
  const int w = tid >> 6, l = tid & 63;
  const int wr = w >> 1, wc = w & 1;
  const int lr = l & 15, lk8 = (l >> 4) * 8;
  const size_t rBase = (size_t)blockIdx.x * 128;
  const int cBase = blockIdx.y * 128;

  f32x4 acc[4][4];
  f32x4 z = {0.f, 0.f, 0.f, 0.f};
#pragma unroll
  for (int m = 0; m < 4; ++m)
#pragma unroll
    for (int n = 0; n < 4; ++n) acc[m][n] = z;

  for (int kb = 0; kb < 32; ++kb) {
    const int k0 = kb * 32;
#pragma unroll
    for (int i = 0; i < 2; ++i) {
      const int chunk = w * 128 + i * 64 + l;
      const int row = chunk >> 2;
      const int c8 = (chunk & 3) * 8;
      gload_lds16(xh + (rBase + row) * 1024 + k0 + c8, &sAh[chunk * 8]);
      gload_lds16(xl + (rBase + row) * 1024 + k0 + c8, &sAl[chunk * 8]);
      gload_lds16(wh + (size_t)(cBase + row) * 1024 + k0 + c8, &sBh[chunk * 8]);
      gload_lds16(wl + (size_t)(cBase + row) * 1024 + k0 + c8, &sBl[chunk * 8]);
    }
    __syncthreads();

    s16x8 ah[4], al[4], bh[4], bl[4];
#pragma unroll
    for (int m = 0; m < 4; ++m) {
      ah[m] = *(const s16x8*)&sAh[(wr * 64 + m * 16 + lr) * 32 + lk8];
      al[m] = *(const s16x8*)&sAl[(wr * 64 + m * 16 + lr) * 32 + lk8];
    }
#pragma unroll
    for (int n = 0; n < 4; ++n) {
      bh[n] = *(const s16x8*)&sBh[(wc * 64 + n * 16 + lr) * 32 + lk8];
      bl[n] = *(const s16x8*)&sBl[(wc * 64 + n * 16 + lr) * 32 + lk8];
    }
#pragma unroll
    for (int m = 0; m < 4; ++m)
#pragma unroll
      for (int n = 0; n < 4; ++n)
        acc[m][n] = __builtin_amdgcn_mfma_f32_16x16x32_bf16(ah[m], bh[n], acc[m][n], 0, 0, 0);
#pragma unroll
    for (int m = 0; m < 4; ++m)
#pragma unroll
      for (int n = 0; n < 4; ++n)
        acc[m][n] = __builtin_amdgcn_mfma_f32_16x16x32_bf16(al[m], bh[n], acc[m][n], 0, 0, 0);
#pragma unroll
    for (int m = 0; m < 4; ++m)
#pragma unroll
      for (int n = 0; n < 4; ++n)
        acc[m][n] = __builtin_amdgcn_mfma_f32_16x16x32_bf16(ah[m], bl[n], acc[m][n], 0, 0, 0);
    __syncthreads();
  }

  const bool isG = (cBase < 1024);
#pragma unroll
  for (int m = 0; m < 4; ++m) {
#pragma unroll
    for (int n = 0; n < 4; ++n) {
      const int col = cBase + wc * 64 + n * 16 + lr;
      const size_t row0 = rBase + wr * 64 + m * 16 + (l >> 4) * 4;
#pragma unroll
      for (int i = 0; i < 4; ++i) {
        float v = acc[m][n][i];
        if (isG) {
          v += bg[col];
          v = 1.f / (1.f + expf(-v));
          G[(row0 + i) * 1024 + col] = v;
        } else {
          v += bi[col - 1024];
          P[(row0 + i) * 1024 + (col - 1024)] = v;
        }
      }
    }
  }
}

// ---------------- persistent recurrence kernel (v2) ----------------
// 32 WGs x 256 threads. WG w owns e-rows [w*32, w*32+32) for all 32 batches.
// Wave kq handles K-quarter; Ws slice (hi+lo) in VGPRs.
// h exchange: agent-scope RELAXED atomics (bypass L1/L2, performed at L3) --
// no fences, no L2 writeback/invalidate. Sync: per-step counter cnt[t];
// publisher does atomicAdd(cnt[t+1]) after __syncthreads (vmcnt drained).
__global__ __launch_bounds__(256, 1) void recur_kernel(
    const float* __restrict__ Ws, const float* __restrict__ bs,
    const float* __restrict__ G, float* out,
    unsigned long long* h_hi, unsigned long long* h_lo, int* cnt) {
  __shared__ float part[4][1024];
  const int w = blockIdx.x;   // e-slice
  const int e0 = w * 32;
  const int tid = threadIdx.x;
  const int kq = tid >> 6;    // wave id = K quarter
  const int l = tid & 63;
  const int lr = l & 15;
  const int lh4 = l >> 4;

  // Ws fragments -> registers (constant over time)
  s16x8 bhi[2][8], blo[2][8];
#pragma unroll
  for (int nt = 0; nt < 2; ++nt) {
#pragma unroll
    for (int c = 0; c < 8; ++c) {
      const int e = e0 + nt * 16 + lr;
      const int k = kq * 256 + c * 32 + lh4 * 8;
      const float* src = Ws + (size_t)e * DIM + k;
      f32x4 v0 = *(const f32x4*)src;
      f32x4 v1 = *(const f32x4*)(src + 4);
      s16x8 vh, vl;
#pragma unroll
      for (int j = 0; j < 4; ++j) {
        unsigned short hb = f2bf(v0[j]);
        vh[j] = (short)hb;
        vl[j] = (short)f2bf(v0[j] - bf2f(hb));
        unsigned short hb2 = f2bf(v1[j]);
        vh[4 + j] = (short)hb2;
        vl[4 + j] = (short)f2bf(v1[j] - bf2f(hb2));
      }
      bhi[nt][c] = vh; blo[nt][c] = vl;
    }
  }

  // epilogue mapping: thread handles outputs [ob][e0+oe .. +4)
  const int ob = (tid * 4) >> 5;
  const int oe = (tid * 4) & 31;
  const f32x4 bs4 = *(const f32x4*)&bs[e0 + oe];
  float hold[4] = {0.f, 0.f, 0.f, 0.f};

  // u64-unit base index into h for this thread's fragment loads
  const int b0 = lr * 256 + kq * 64 + lh4 * 2;
  const int sBase = ob * 256 + ((e0 + oe) >> 2);  // u64-unit store index

  // G/P prefetch pipeline (one step ahead)
  size_t gp_idx = ((size_t)ob * SEQ) * DIM + e0 + oe;  // t = 0
  f32x4 g4 = *(const f32x4*)&G[gp_idx];
  f32x4 p4 = *(const f32x4*)&out[gp_idx];

#pragma unroll 1
  for (int t = 0; t < SEQ; ++t) {
    // ---- wait for h_t fully published (single counter, tid0 polls) ----
    if (tid == 0) {
      while (__hip_atomic_load(&cnt[t], __ATOMIC_RELAXED,
                               __HIP_MEMORY_SCOPE_AGENT) < 32) { }
    }
    __builtin_amdgcn_s_barrier();
    asm volatile("" ::: "memory");  // compiler-only fence (no cache ops)

    // ---- load h_t fragments (agent-scope atomics -> L3, coherent) ----
    const unsigned long long* Hh = h_hi + (size_t)(t & 1) * 8192;
    const unsigned long long* Hl = h_lo + (size_t)(t & 1) * 8192;
    s16x8 ah[2][8], al[2][8];
#pragma unroll
    for (int c = 0; c < 8; ++c) {
#pragma unroll
      for (int mt = 0; mt < 2; ++mt) {
        const int idx = b0 + mt * 4096 + c * 8;
        union { unsigned long long q[2]; s16x8 v; } uh, ul;
        uh.q[0] = __hip_atomic_load(&Hh[idx],     __ATOMIC_RELAXED, __HIP_MEMORY_SCOPE_AGENT);
        uh.q[1] = __hip_atomic_load(&Hh[idx + 1], __ATOMIC_RELAXED, __HIP_MEMORY_SCOPE_AGENT);
        ul.q[0] = __hip_atomic_load(&Hl[idx],     __ATOMIC_RELAXED, __HIP_MEMORY_SCOPE_AGENT);
        ul.q[1] = __hip_atomic_load(&Hl[idx + 1], __ATOMIC_RELAXED, __HIP_MEMORY_SCOPE_AGENT);
        ah[mt][c] = uh.v; al[mt][c] = ul.v;
      }
    }

    // ---- prefetch g,p for t+1 (overlaps MFMA) ----
    const size_t gp_next = gp_idx + ((t + 1 < SEQ) ? DIM : 0);
    const f32x4 gn = *(const f32x4*)&G[gp_next];
    const f32x4 pn = *(const f32x4*)&out[gp_next];

    // ---- 3-term split-bf16 MFMA ----
    f32x4 z = {0.f, 0.f, 0.f, 0.f};
    f32x4 aA[2][2], aB[2][2], aC[2][2];
#pragma unroll
    for (int mt = 0; mt < 2; ++mt)
#pragma unroll
      for (int nt = 0; nt < 2; ++nt) { aA[mt][nt] = z; aB[mt][nt] = z; aC[mt][nt] = z; }

#pragma unroll
    for (int c = 0; c < 8; ++c) {
#pragma unroll
      for (int mt = 0; mt < 2; ++mt)
#pragma unroll
        for (int nt = 0; nt < 2; ++nt) {
          aA[mt][nt] = __builtin_amdgcn_mfma_f32_16x16x32_bf16(ah[mt][c], bhi[nt][c], aA[mt][nt], 0, 0, 0);
          aB[mt][nt] = __builtin_amdgcn_mfma_f32_16x16x32_bf16(al[mt][c], bhi[nt][c], aB[mt][nt], 0, 0, 0);
          aC[mt][nt] = __builtin_amdgcn_mfma_f32_16x16x32_bf16(ah[mt][c], blo[nt][c], aC[mt][nt], 0, 0, 0);
        }
    }

    // ---- cross-wave K reduce via LDS ----
#pragma unroll
    for (int mt = 0; mt < 2; ++mt)
#pragma unroll
      for (int nt = 0; nt < 2; ++nt) {
        f32x4 v = aA[mt][nt] + aB[mt][nt] + aC[mt][nt];
#pragma unroll
        for (int i = 0; i < 4; ++i)
          part[kq][(mt * 16 + lh4 * 4 + i) * 32 + nt * 16 + lr] = v[i];
      }
    asm volatile("s_waitcnt lgkmcnt(0)" ::: "memory");
    __builtin_amdgcn_s_barrier();
    asm volatile("" ::: "memory");

    f32x4 r = *(const f32x4*)&part[0][tid * 4];
    r = r + *(const f32x4*)&part[1][tid * 4];
    r = r + *(const f32x4*)&part[2][tid * 4];
    r = r + *(const f32x4*)&part[3][tid * 4];

    // ---- epilogue ----
    f32x4 hn;
#pragma unroll
    for (int j = 0; j < 4; ++j) {
      const float mix = r[j] + bs4[j] + p4[j];
      const float g = g4[j];
      const float v = g * mix + (1.f - g) * hold[j];
      hold[j] = v; hn[j] = v;
    }

    // publish h_{t+1} first (critical path), then emit
    union { u16x4 v; unsigned long long q; } sh, sl;
#pragma unroll
    for (int j = 0; j < 4; ++j) {
      unsigned short hb = f2bf(hn[j]);
      sh.v[j] = hb; sl.v[j] = f2bf(hn[j] - bf2f(hb));
    }
    const int sidx = ((t + 1) & 1) * 8192 + sBase;
    __hip_atomic_store(&h_hi[sidx], sh.q, __ATOMIC_RELAXED, __HIP_MEMORY_SCOPE_AGENT);
    __hip_atomic_store(&h_lo[sidx], sl.q, __ATOMIC_RELAXED, __HIP_MEMORY_SCOPE_AGENT);

    *(f32x4*)&out[gp_idx] = hn;  // emitted (overwrites consumed P slot)
    if (t == SEQ - 1)
      *(f32x4*)&out[BSD + (size_t)ob * DIM + e0 + oe] = hn;

    g4 = gn; p4 = pn; gp_idx = gp_next;

    // ---- drain all stores (vmcnt(0) implied), then publish counter ----
    __syncthreads();
    if (tid == 0 && t < SEQ - 1) {
      __hip_atomic_fetch_add(&cnt[t + 1], 1, __ATOMIC_RELAXED,
                             __HIP_MEMORY_SCOPE_AGENT);
    }
  }
}

// ---------------- launch ----------------
extern "C" void kernel_launch(void* const* d_in, const int* in_sizes, int n_in,
                              void* d_out, int out_size, void* d_ws, size_t ws_size,
                              hipStream_t stream) {
  (void)in_sizes; (void)n_in; (void)out_size; (void)ws_size;
  const float* x  = (const float*)d_in[0];
  const float* Wg = (const float*)d_in[1];
  const float* bg = (const float*)d_in[2];
  const float* Ws = (const float*)d_in[3];
  const float* bs = (const float*)d_in[4];
  const float* Wi = (const float*)d_in[5];
  const float* bi = (const float*)d_in[6];
  float* out = (float*)d_out;
  char* ws = (char*)d_ws;

  // ws layout (bytes), max offset 277086208 (same as R1):
  unsigned short* xh   = (unsigned short*)(ws);              // 64 MB
  unsigned short* xl   = (unsigned short*)(ws + 67108864);   // 64 MB
  unsigned short* wh   = (unsigned short*)(ws + 134217728);  // 4 MB (dead after gemm)
  unsigned short* wl   = (unsigned short*)(ws + 138412032);  // 4 MB (dead after gemm)
  float*          G    = (float*)(ws + 142606336);           // 128 MB
  unsigned long long* h_hi = (unsigned long long*)(ws + 276824064);  // 128 KB (2 parities)
  unsigned long long* h_lo = (unsigned long long*)(ws + 276955136);  // 128 KB
  int*            cnt  = (int*)(ws + 134217728);             // 4.1 KB, overlaps wh (init AFTER gemm)

  hipLaunchKernelGGL(split_x_kernel, dim3(4096), dim3(256), 0, stream,
                     x, xh, xl, (long)(BSD / 4));
  hipLaunchKernelGGL(split_w_kernel, dim3(2048), dim3(256), 0, stream, Wg, Wi, wh, wl);
  hipLaunchKernelGGL(gemm_gp_kernel, dim3(256, 16), dim3(256), 0, stream,
                     xh, xl, wh, wl, bg, bi, G, out);
  hipLaunchKernelGGL(init_kernel, dim3(64), dim3(256), 0, stream, h_hi, h_lo, cnt);
  hipLaunchKernelGGL(recur_kernel, dim3(32), dim3(256), 0, stream,
                     Ws, bs, G, out, h_hi, h_lo, cnt);
}

// Round 3
// 6889.939 us; speedup vs baseline: 1.3621x; 1.3621x over previous
//
#include <hip/hip_runtime.h>
#include <cstdint>

// B=32, S=1024, D=1024 ContractiveSequenceMixer.
// R3: h exchange via PLAIN coalescing global loads/stores with sc0 sc1
// (L1/L2-bypass, performed at fabric coherence point). Per-producer flags,
// no atomic RMW on the critical path. (R1 fences / R2 per-lane atomics both
// ~8.7us/step pure stall.)

#define BATCH 32
#define SEQ   1024
#define DIM   1024
static const size_t BSD = (size_t)BATCH * SEQ * DIM; // 33554432

typedef short  s16x8 __attribute__((ext_vector_type(8)));
typedef unsigned short u16x4 __attribute__((ext_vector_type(4)));
typedef float  f32x4 __attribute__((ext_vector_type(4)));

__device__ __forceinline__ unsigned short f2bf(float f) {
  union { float f; unsigned int u; } v; v.f = f;
  unsigned int r = v.u + 0x7fffu + ((v.u >> 16) & 1u);  // RNE
  return (unsigned short)(r >> 16);
}
__device__ __forceinline__ float bf2f(unsigned short h) {
  union { unsigned int u; float f; } v; v.u = ((unsigned int)h) << 16; return v.f;
}

__device__ __forceinline__ void gload_lds16(const void* g, void* l) {
  __builtin_amdgcn_global_load_lds(
      (const __attribute__((address_space(1))) void*)g,
      (__attribute__((address_space(3))) void*)l, 16, 0, 0);
}

// coherent (fabric-level) access helpers
#define HLOAD(dst, base, IMM)                                              \
  asm volatile("global_load_dwordx4 %0, %1, off offset:" IMM " sc0 sc1"    \
               : "=v"(dst) : "v"(base))
#define HL8(arr, base)        \
  HLOAD(arr[0], base, "0");   \
  HLOAD(arr[1], base, "64");  \
  HLOAD(arr[2], base, "128"); \
  HLOAD(arr[3], base, "192"); \
  HLOAD(arr[4], base, "256"); \
  HLOAD(arr[5], base, "320"); \
  HLOAD(arr[6], base, "384"); \
  HLOAD(arr[7], base, "448")

__device__ __forceinline__ void cstore8(void* p, u16x4 v) {
  asm volatile("global_store_dwordx2 %0, %1, off sc0 sc1"
               :: "v"(p), "v"(v) : "memory");
}
__device__ __forceinline__ void cstore4(void* p, int v) {
  asm volatile("global_store_dword %0, %1, off sc0 sc1"
               :: "v"(p), "v"(v) : "memory");
}
__device__ __forceinline__ int cload4(const void* p) {
  int v;
  asm volatile("global_load_dword %0, %1, off sc0 sc1\n\ts_waitcnt vmcnt(0)"
               : "=v"(v) : "v"(p) : "memory");
  return v;
}

// ---------------- prep kernels ----------------
__global__ void split_x_kernel(const float* __restrict__ x,
                               unsigned short* __restrict__ xh,
                               unsigned short* __restrict__ xl, long n4) {
  long i = (long)blockIdx.x * blockDim.x + threadIdx.x;
  const long stride = (long)gridDim.x * blockDim.x;
  for (; i < n4; i += stride) {
    f32x4 v = *(const f32x4*)&x[i * 4];
    u16x4 vh, vl;
#pragma unroll
    for (int j = 0; j < 4; ++j) {
      unsigned short hb = f2bf(v[j]);
      vh[j] = hb; vl[j] = f2bf(v[j] - bf2f(hb));
    }
    *(u16x4*)&xh[i * 4] = vh;
    *(u16x4*)&xl[i * 4] = vl;
  }
}

__global__ void split_w_kernel(const float* __restrict__ Wg,
                               const float* __restrict__ Wi,
                               unsigned short* __restrict__ wh,
                               unsigned short* __restrict__ wl) {
  long i = (long)blockIdx.x * blockDim.x + threadIdx.x; // 524288 float4 groups
  if (i >= (long)(2048 * 1024 / 4)) return;
  long flat = i * 4;
  int row = (int)(flat >> 10);
  int col = (int)(flat & 1023);
  const float* src = (row < 1024) ? &Wg[(size_t)row * 1024 + col]
                                  : &Wi[(size_t)(row - 1024) * 1024 + col];
  f32x4 v = *(const f32x4*)src;
  u16x4 vh, vl;
#pragma unroll
  for (int j = 0; j < 4; ++j) {
    unsigned short hb = f2bf(v[j]);
    vh[j] = hb; vl[j] = f2bf(v[j] - bf2f(hb));
  }
  *(u16x4*)&wh[flat] = vh;
  *(u16x4*)&wl[flat] = vl;
}

// h/flags must be written with sc0sc1 (bypassing readers can't see dirty L2).
__global__ void init_kernel(unsigned short* h_hi, unsigned short* h_lo,
                            int* flags) {
  int i = blockIdx.x * blockDim.x + threadIdx.x;  // 16384 launched
  u16x4 z4 = {0, 0, 0, 0};
  if (i < 16384) {                 // 2 parities x 32768 ushort, 4 per thread
    cstore8(h_hi + (size_t)i * 4, z4);
    cstore8(h_lo + (size_t)i * 4, z4);
  }
  if (i < 512) cstore4(flags + i, 0);
}

// ---------------- fused G/P GEMM (split-bf16, 3-term) ----------------
__global__ __launch_bounds__(256) void gemm_gp_kernel(
    const unsigned short* __restrict__ xh, const unsigned short* __restrict__ xl,
    const unsigned short* __restrict__ wh, const unsigned short* __restrict__ wl,
    const float* __restrict__ bg, const float* __restrict__ bi,
    float* __restrict__ G, float* __restrict__ P) {
  __shared__ unsigned short sAh[128 * 32], sAl[128 * 32], sBh[128 * 32], sBl[128 * 32];
  const int tid = threadIdx.x;
  const int w = tid >> 6, l = tid & 63;
  const int wr = w >> 1, wc = w & 1;
  const int lr = l & 15, lk8 = (l >> 4) * 8;
  const size_t rBase = (size_t)blockIdx.x * 128;
  const int cBase = blockIdx.y * 128;

  f32x4 acc[4][4];
  f32x4 z = {0.f, 0.f, 0.f, 0.f};
#pragma unroll
  for (int m = 0; m < 4; ++m)
#pragma unroll
    for (int n = 0; n < 4; ++n) acc[m][n] = z;

  for (int kb = 0; kb < 32; ++kb) {
    const int k0 = kb * 32;
#pragma unroll
    for (int i = 0; i < 2; ++i) {
      const int chunk = w * 128 + i * 64 + l;
      const int row = chunk >> 2;
      const int c8 = (chunk & 3) * 8;
      gload_lds16(xh + (rBase + row) * 1024 + k0 + c8, &sAh[chunk * 8]);
      gload_lds16(xl + (rBase + row) * 1024 + k0 + c8, &sAl[chunk * 8]);
      gload_lds16(wh + (size_t)(cBase + row) * 1024 + k0 + c8, &sBh[chunk * 8]);
      gload_lds16(wl + (size_t)(cBase + row) * 1024 + k0 + c8, &sBl[chunk * 8]);
    }
    __syncthreads();

    s16x8 ah[4], al[4], bh[4], bl[4];
#pragma unroll
    for (int m = 0; m < 4; ++m) {
      ah[m] = *(const s16x8*)&sAh[(wr * 64 + m * 16 + lr) * 32 + lk8];
      al[m] = *(const s16x8*)&sAl[(wr * 64 + m * 16 + lr) * 32 + lk8];
    }
#pragma unroll
    for (int n = 0; n < 4; ++n) {
      bh[n] = *(const s16x8*)&sBh[(wc * 64 + n * 16 + lr) * 32 + lk8];
      bl[n] = *(const s16x8*)&sBl[(wc * 64 + n * 16 + lr) * 32 + lk8];
    }
#pragma unroll
    for (int m = 0; m < 4; ++m)
#pragma unroll
      for (int n = 0; n < 4; ++n)
        acc[m][n] = __builtin_amdgcn_mfma_f32_16x16x32_bf16(ah[m], bh[n], acc[m][n], 0, 0, 0);
#pragma unroll
    for (int m = 0; m < 4; ++m)
#pragma unroll
      for (int n = 0; n < 4; ++n)
        acc[m][n] = __builtin_amdgcn_mfma_f32_16x16x32_bf16(al[m], bh[n], acc[m][n], 0, 0, 0);
#pragma unroll
    for (int m = 0; m < 4; ++m)
#pragma unroll
      for (int n = 0; n < 4; ++n)
        acc[m][n] = __builtin_amdgcn_mfma_f32_16x16x32_bf16(ah[m], bl[n], acc[m][n], 0, 0, 0);
    __syncthreads();
  }

  const bool isG = (cBase < 1024);
#pragma unroll
  for (int m = 0; m < 4; ++m) {
#pragma unroll
    for (int n = 0; n < 4; ++n) {
      const int col = cBase + wc * 64 + n * 16 + lr;
      const size_t row0 = rBase + wr * 64 + m * 16 + (l >> 4) * 4;
#pragma unroll
      for (int i = 0; i < 4; ++i) {
        float v = acc[m][n][i];
        if (isG) {
          v += bg[col];
          v = 1.f / (1.f + expf(-v));
          G[(row0 + i) * 1024 + col] = v;
        } else {
          v += bi[col - 1024];
          P[(row0 + i) * 1024 + (col - 1024)] = v;
        }
      }
    }
  }
}

// ---------------- persistent recurrence kernel (v3) ----------------
// 32 WGs x 256 threads. WG w owns e-rows [w*32,+32) for all batches.
// h exchange: sc0sc1 coalescing loads/stores (fabric-coherent).
// Sync: per-producer flags (64B apart); wave0 polls 32 flags w/ one load.
__global__ __launch_bounds__(256, 1) void recur_kernel(
    const float* __restrict__ Ws, const float* __restrict__ bs,
    const float* __restrict__ G, float* out,
    unsigned short* h_hi, unsigned short* h_lo, int* flags) {
  __shared__ float part[4][1024];
  const int w = blockIdx.x;   // e-slice
  const int e0 = w * 32;
  const int tid = threadIdx.x;
  const int kq = tid >> 6;    // wave id = K quarter
  const int l = tid & 63;
  const int lr = l & 15;
  const int lh4 = l >> 4;

  // Ws fragments -> registers (constant over time)
  s16x8 bhi[2][8], blo[2][8];
#pragma unroll
  for (int nt = 0; nt < 2; ++nt) {
#pragma unroll
    for (int c = 0; c < 8; ++c) {
      const int e = e0 + nt * 16 + lr;
      const int k = kq * 256 + c * 32 + lh4 * 8;
      const float* src = Ws + (size_t)e * DIM + k;
      f32x4 v0 = *(const f32x4*)src;
      f32x4 v1 = *(const f32x4*)(src + 4);
      s16x8 vh, vl;
#pragma unroll
      for (int j = 0; j < 4; ++j) {
        unsigned short hb = f2bf(v0[j]);
        vh[j] = (short)hb;
        vl[j] = (short)f2bf(v0[j] - bf2f(hb));
        unsigned short hb2 = f2bf(v1[j]);
        vh[4 + j] = (short)hb2;
        vl[4 + j] = (short)f2bf(v1[j] - bf2f(hb2));
      }
      bhi[nt][c] = vh; blo[nt][c] = vl;
    }
  }

  // epilogue mapping: thread handles outputs [ob][e0+oe .. +4)
  const int ob = (tid * 4) >> 5;
  const int oe = (tid * 4) & 31;
  const f32x4 bs4 = *(const f32x4*)&bs[e0 + oe];
  float hold[4] = {0.f, 0.f, 0.f, 0.f};

  // per-lane element offset for fragment loads (mt=0 base; mt=1 = +16384)
  const int lane_off = lr * 1024 + kq * 256 + lh4 * 8;
  const int s_off = ob * 1024 + e0 + oe;  // element offset for h store

  // G/P prefetch pipeline (one step ahead)
  size_t gp_idx = ((size_t)ob * SEQ) * DIM + e0 + oe;  // t = 0
  f32x4 g4 = *(const f32x4*)&G[gp_idx];
  f32x4 p4 = *(const f32x4*)&out[gp_idx];

#pragma unroll 1
  for (int t = 0; t < SEQ; ++t) {
    // ---- wait for h_t fully published: wave0 polls 32 flags ----
    if (tid < 64) {
      const int* fp = flags + ((tid & 31) << 4);
      int v;
      do { v = cload4(fp); } while (__any(v < t));
    }
    __builtin_amdgcn_s_barrier();
    __builtin_amdgcn_sched_barrier(0);

    // ---- prefetch g,p for t+1 (resolves during this step) ----
    const size_t gp_next = gp_idx + ((t + 1 < SEQ) ? DIM : 0);
    const f32x4 gn = *(const f32x4*)&G[gp_next];
    const f32x4 pn = *(const f32x4*)&out[gp_next];

    // ---- load h_t fragments (coalesced, fabric-coherent) ----
    const unsigned short* Hh = h_hi + (size_t)(t & 1) * 32768 + lane_off;
    const unsigned short* Hl = h_lo + (size_t)(t & 1) * 32768 + lane_off;
    s16x8 ah[2][8], al[2][8];
    HL8(ah[0], Hh);
    HL8(ah[1], (Hh + 16384));
    HL8(al[0], Hl);
    HL8(al[1], (Hl + 16384));
    asm volatile("s_waitcnt vmcnt(0)" ::: "memory");
    __builtin_amdgcn_sched_barrier(0);

    // ---- 3-term split-bf16 MFMA ----
    f32x4 z = {0.f, 0.f, 0.f, 0.f};
    f32x4 aA[2][2], aB[2][2], aC[2][2];
#pragma unroll
    for (int mt = 0; mt < 2; ++mt)
#pragma unroll
      for (int nt = 0; nt < 2; ++nt) { aA[mt][nt] = z; aB[mt][nt] = z; aC[mt][nt] = z; }

#pragma unroll
    for (int c = 0; c < 8; ++c) {
#pragma unroll
      for (int mt = 0; mt < 2; ++mt)
#pragma unroll
        for (int nt = 0; nt < 2; ++nt) {
          aA[mt][nt] = __builtin_amdgcn_mfma_f32_16x16x32_bf16(ah[mt][c], bhi[nt][c], aA[mt][nt], 0, 0, 0);
          aB[mt][nt] = __builtin_amdgcn_mfma_f32_16x16x32_bf16(al[mt][c], bhi[nt][c], aB[mt][nt], 0, 0, 0);
          aC[mt][nt] = __builtin_amdgcn_mfma_f32_16x16x32_bf16(ah[mt][c], blo[nt][c], aC[mt][nt], 0, 0, 0);
        }
    }

    // ---- cross-wave K reduce via LDS ----
#pragma unroll
    for (int mt = 0; mt < 2; ++mt)
#pragma unroll
      for (int nt = 0; nt < 2; ++nt) {
        f32x4 v = aA[mt][nt] + aB[mt][nt] + aC[mt][nt];
#pragma unroll
        for (int i = 0; i < 4; ++i)
          part[kq][(mt * 16 + lh4 * 4 + i) * 32 + nt * 16 + lr] = v[i];
      }
    asm volatile("s_waitcnt lgkmcnt(0)" ::: "memory");
    __builtin_amdgcn_s_barrier();
    __builtin_amdgcn_sched_barrier(0);

    f32x4 r = *(const f32x4*)&part[0][tid * 4];
    r = r + *(const f32x4*)&part[1][tid * 4];
    r = r + *(const f32x4*)&part[2][tid * 4];
    r = r + *(const f32x4*)&part[3][tid * 4];

    // ---- epilogue ----
    f32x4 hn;
#pragma unroll
    for (int j = 0; j < 4; ++j) {
      const float mix = r[j] + bs4[j] + p4[j];
      const float g = g4[j];
      const float v = g * mix + (1.f - g) * hold[j];
      hold[j] = v; hn[j] = v;
    }

    // publish h_{t+1} (write-through), then emit
    u16x4 sh, sl;
#pragma unroll
    for (int j = 0; j < 4; ++j) {
      unsigned short hb = f2bf(hn[j]);
      sh[j] = hb; sl[j] = f2bf(hn[j] - bf2f(hb));
    }
    unsigned short* sp = h_hi + (size_t)((t + 1) & 1) * 32768 + s_off;
    cstore8(sp, sh);
    unsigned short* spl = h_lo + (size_t)((t + 1) & 1) * 32768 + s_off;
    cstore8(spl, sl);

    *(f32x4*)&out[gp_idx] = hn;  // emitted (overwrites consumed P slot)
    if (t == SEQ - 1)
      *(f32x4*)&out[BSD + (size_t)ob * DIM + e0 + oe] = hn;

    g4 = gn; p4 = pn; gp_idx = gp_next;

    // ---- drain all stores (vmcnt(0) in barrier), then publish flag ----
    __syncthreads();
    if (tid == 0 && t < SEQ - 1)
      cstore4(flags + (w << 4), t + 1);
  }
}

// ---------------- launch ----------------
extern "C" void kernel_launch(void* const* d_in, const int* in_sizes, int n_in,
                              void* d_out, int out_size, void* d_ws, size_t ws_size,
                              hipStream_t stream) {
  (void)in_sizes; (void)n_in; (void)out_size; (void)ws_size;
  const float* x  = (const float*)d_in[0];
  const float* Wg = (const float*)d_in[1];
  const float* bg = (const float*)d_in[2];
  const float* Ws = (const float*)d_in[3];
  const float* bs = (const float*)d_in[4];
  const float* Wi = (const float*)d_in[5];
  const float* bi = (const float*)d_in[6];
  float* out = (float*)d_out;
  char* ws = (char*)d_ws;

  unsigned short* xh   = (unsigned short*)(ws);              // 64 MB
  unsigned short* xl   = (unsigned short*)(ws + 67108864);   // 64 MB
  unsigned short* wh   = (unsigned short*)(ws + 134217728);  // 4 MB (dead after gemm)
  unsigned short* wl   = (unsigned short*)(ws + 138412032);  // 4 MB (dead after gemm)
  float*          G    = (float*)(ws + 142606336);           // 128 MB
  unsigned short* h_hi = (unsigned short*)(ws + 276824064);  // 128 KB (2 parities)
  unsigned short* h_lo = (unsigned short*)(ws + 276955136);  // 128 KB
  int*            flags= (int*)(ws + 134217728);             // 2 KB, overlaps wh (init AFTER gemm)

  hipLaunchKernelGGL(split_x_kernel, dim3(4096), dim3(256), 0, stream,
                     x, xh, xl, (long)(BSD / 4));
  hipLaunchKernelGGL(split_w_kernel, dim3(2048), dim3(256), 0, stream, Wg, Wi, wh, wl);
  hipLaunchKernelGGL(gemm_gp_kernel, dim3(256, 16), dim3(256), 0, stream,
                     xh, xl, wh, wl, bg, bi, G, out);
  hipLaunchKernelGGL(init_kernel, dim3(64), dim3(256), 0, stream, h_hi, h_lo, flags);
  hipLaunchKernelGGL(recur_kernel, dim3(32), dim3(256), 0, stream,
                     Ws, bs, G, out, h_hi, h_lo, flags);
}

// Round 5
// 3785.929 us; speedup vs baseline: 2.4788x; 1.8199x over previous
//
#include <hip/hip_runtime.h>
#include <cstdint>

// B=32, S=1024, D=1024 ContractiveSequenceMixer.
// R5: batch-grouped recurrence with PLACEMENT-INDEPENDENT sync.
//  - 256 WGs; group g = bid>>5 owns batches 4g..4g+3; rank = bid&31 owns
//    32 e-rows; wave kq = K-quarter (polls only its 8 producer flags).
//  - h/flags exchanged via R3-proven sc0sc1 (L3 coherence point) ops.
//  - No XCC_ID, no rank atomics, no dynamic LDS, no start barrier
//    (R4's XCD-pinned sc0-L2 scheme deadlocked: correctness must not
//    depend on WG->XCD placement).
// Per-WG per-step h read: 16KB (vs R3's 128KB).

#define BATCH 32
#define SEQ   1024
#define DIM   1024
static const size_t BSD = (size_t)BATCH * SEQ * DIM; // 33554432

typedef short  s16x8 __attribute__((ext_vector_type(8)));
typedef unsigned short u16x4 __attribute__((ext_vector_type(4)));
typedef float  f32x4 __attribute__((ext_vector_type(4)));

__device__ __forceinline__ unsigned short f2bf(float f) {
  union { float f; unsigned int u; } v; v.f = f;
  unsigned int r = v.u + 0x7fffu + ((v.u >> 16) & 1u);  // RNE
  return (unsigned short)(r >> 16);
}
__device__ __forceinline__ float bf2f(unsigned short h) {
  union { unsigned int u; float f; } v; v.u = ((unsigned int)h) << 16; return v.f;
}

__device__ __forceinline__ void gload_lds16(const void* g, void* l) {
  __builtin_amdgcn_global_load_lds(
      (const __attribute__((address_space(1))) void*)g,
      (__attribute__((address_space(3))) void*)l, 16, 0, 0);
}

// ---- L3-coherent helpers (proven in R3) ----
#define HLOAD(dst, base, IMM)                                              \
  asm volatile("global_load_dwordx4 %0, %1, off offset:" IMM " sc0 sc1"    \
               : "=v"(dst) : "v"(base))
#define HL8(arr, base)        \
  HLOAD(arr[0], base, "0");   \
  HLOAD(arr[1], base, "64");  \
  HLOAD(arr[2], base, "128"); \
  HLOAD(arr[3], base, "192"); \
  HLOAD(arr[4], base, "256"); \
  HLOAD(arr[5], base, "320"); \
  HLOAD(arr[6], base, "384"); \
  HLOAD(arr[7], base, "448")

__device__ __forceinline__ void cstore8(void* p, u16x4 v) {
  asm volatile("global_store_dwordx2 %0, %1, off sc0 sc1"
               :: "v"(p), "v"(v) : "memory");
}
__device__ __forceinline__ void cstore4(void* p, int v) {
  asm volatile("global_store_dword %0, %1, off sc0 sc1"
               :: "v"(p), "v"(v) : "memory");
}
__device__ __forceinline__ void cstore4u(void* p, unsigned v) {
  asm volatile("global_store_dword %0, %1, off sc0 sc1"
               :: "v"(p), "v"(v) : "memory");
}
__device__ __forceinline__ int cload4(const void* p) {
  int v;
  asm volatile("global_load_dword %0, %1, off sc0 sc1\n\ts_waitcnt vmcnt(0)"
               : "=v"(v) : "v"(p) : "memory");
  return v;
}

// ---------------- prep kernels ----------------
__global__ void split_x_kernel(const float* __restrict__ x,
                               unsigned short* __restrict__ xh,
                               unsigned short* __restrict__ xl, long n4) {
  long i = (long)blockIdx.x * blockDim.x + threadIdx.x;
  const long stride = (long)gridDim.x * blockDim.x;
  for (; i < n4; i += stride) {
    f32x4 v = *(const f32x4*)&x[i * 4];
    u16x4 vh, vl;
#pragma unroll
    for (int j = 0; j < 4; ++j) {
      unsigned short hb = f2bf(v[j]);
      vh[j] = hb; vl[j] = f2bf(v[j] - bf2f(hb));
    }
    *(u16x4*)&xh[i * 4] = vh;
    *(u16x4*)&xl[i * 4] = vl;
  }
}

__global__ void split_w_kernel(const float* __restrict__ Wg,
                               const float* __restrict__ Wi,
                               unsigned short* __restrict__ wh,
                               unsigned short* __restrict__ wl) {
  long i = (long)blockIdx.x * blockDim.x + threadIdx.x; // 524288 float4 groups
  if (i >= (long)(2048 * 1024 / 4)) return;
  long flat = i * 4;
  int row = (int)(flat >> 10);
  int col = (int)(flat & 1023);
  const float* src = (row < 1024) ? &Wg[(size_t)row * 1024 + col]
                                  : &Wi[(size_t)(row - 1024) * 1024 + col];
  f32x4 v = *(const f32x4*)src;
  u16x4 vh, vl;
#pragma unroll
  for (int j = 0; j < 4; ++j) {
    unsigned short hb = f2bf(v[j]);
    vh[j] = hb; vl[j] = f2bf(v[j] - bf2f(hb));
  }
  *(u16x4*)&wh[flat] = vh;
  *(u16x4*)&wl[flat] = vl;
}

// zero h (both parities, all groups) + flags, all via sc0sc1 (L3).
// h_hi/h_lo: [2 parity][8 group][4 batch][1024 e] ushort = 65536 each.
__global__ void init_kernel(unsigned short* h_hi, unsigned short* h_lo,
                            int* flags) {
  int i = blockIdx.x * blockDim.x + threadIdx.x;  // 16384 launched
  u16x4 z4 = {0, 0, 0, 0};
  if (i < 16384) {
    cstore8(h_hi + (size_t)i * 4, z4);
    cstore8(h_lo + (size_t)i * 4, z4);
  }
  if (i < 4096) cstore4(flags + i, 0);
}

// ---------------- fused G/P GEMM (split-bf16, 3-term) ----------------
__global__ __launch_bounds__(256) void gemm_gp_kernel(
    const unsigned short* __restrict__ xh, const unsigned short* __restrict__ xl,
    const unsigned short* __restrict__ wh, const unsigned short* __restrict__ wl,
    const float* __restrict__ bg, const float* __restrict__ bi,
    float* __restrict__ G, float* __restrict__ P) {
  __shared__ unsigned short sAh[128 * 32], sAl[128 * 32], sBh[128 * 32], sBl[128 * 32];
  const int tid = threadIdx.x;
  const int w = tid >> 6, l = tid & 63;
  const int wr = w >> 1, wc = w & 1;
  const int lr = l & 15, lk8 = (l >> 4) * 8;
  const size_t rBase = (size_t)blockIdx.x * 128;
  const int cBase = blockIdx.y * 128;

  f32x4 acc[4][4];
  f32x4 z = {0.f, 0.f, 0.f, 0.f};
#pragma unroll
  for (int m = 0; m < 4; ++m)
#pragma unroll
    for (int n = 0; n < 4; ++n) acc[m][n] = z;

  for (int kb = 0; kb < 32; ++kb) {
    const int k0 = kb * 32;
#pragma unroll
    for (int i = 0; i < 2; ++i) {
      const int chunk = w * 128 + i * 64 + l;
      const int row = chunk >> 2;
      const int c8 = (chunk & 3) * 8;
      gload_lds16(xh + (rBase + row) * 1024 + k0 + c8, &sAh[chunk * 8]);
      gload_lds16(xl + (rBase + row) * 1024 + k0 + c8, &sAl[chunk * 8]);
      gload_lds16(wh + (size_t)(cBase + row) * 1024 + k0 + c8, &sBh[chunk * 8]);
      gload_lds16(wl + (size_t)(cBase + row) * 1024 + k0 + c8, &sBl[chunk * 8]);
    }
    __syncthreads();

    s16x8 ah[4], al[4], bh[4], bl[4];
#pragma unroll
    for (int m = 0; m < 4; ++m) {
      ah[m] = *(const s16x8*)&sAh[(wr * 64 + m * 16 + lr) * 32 + lk8];
      al[m] = *(const s16x8*)&sAl[(wr * 64 + m * 16 + lr) * 32 + lk8];
    }
#pragma unroll
    for (int n = 0; n < 4; ++n) {
      bh[n] = *(const s16x8*)&sBh[(wc * 64 + n * 16 + lr) * 32 + lk8];
      bl[n] = *(const s16x8*)&sBl[(wc * 64 + n * 16 + lr) * 32 + lk8];
    }
#pragma unroll
    for (int m = 0; m < 4; ++m)
#pragma unroll
      for (int n = 0; n < 4; ++n)
        acc[m][n] = __builtin_amdgcn_mfma_f32_16x16x32_bf16(ah[m], bh[n], acc[m][n], 0, 0, 0);
#pragma unroll
    for (int m = 0; m < 4; ++m)
#pragma unroll
      for (int n = 0; n < 4; ++n)
        acc[m][n] = __builtin_amdgcn_mfma_f32_16x16x32_bf16(al[m], bh[n], acc[m][n], 0, 0, 0);
#pragma unroll
    for (int m = 0; m < 4; ++m)
#pragma unroll
      for (int n = 0; n < 4; ++n)
        acc[m][n] = __builtin_amdgcn_mfma_f32_16x16x32_bf16(ah[m], bl[n], acc[m][n], 0, 0, 0);
    __syncthreads();
  }

  const bool isG = (cBase < 1024);
#pragma unroll
  for (int m = 0; m < 4; ++m) {
#pragma unroll
    for (int n = 0; n < 4; ++n) {
      const int col = cBase + wc * 64 + n * 16 + lr;
      const size_t row0 = rBase + wr * 64 + m * 16 + (l >> 4) * 4;
#pragma unroll
      for (int i = 0; i < 4; ++i) {
        float v = acc[m][n][i];
        if (isG) {
          v += bg[col];
          v = 1.f / (1.f + expf(-v));
          G[(row0 + i) * 1024 + col] = v;
        } else {
          v += bi[col - 1024];
          P[(row0 + i) * 1024 + (col - 1024)] = v;
        }
      }
    }
  }
}

// ---------------- persistent recurrence kernel (v5) ----------------
// 256 WGs x 256 thr. group g = bid>>5 (batches 4g..4g+3), rank = bid&31
// (e-rows rank*32..+32). Wave kq = K-quarter, polls its 8 producers.
// h layout: [parity][group][batch(4)][1024] bf16 hi / lo.
__global__ __launch_bounds__(256) void recur_kernel(
    const float* __restrict__ Ws, const float* __restrict__ bs,
    const float* __restrict__ G, float* out,
    unsigned short* h_hi, unsigned short* h_lo, int* flags) {
  __shared__ float part[2 * 4 * 4 * 32];  // [parity][kq][batch][32 e]
  const int g = blockIdx.x >> 5;
  const int rank = blockIdx.x & 31;
  const int tid = threadIdx.x;
  const int kq = tid >> 6, l = tid & 63;
  const int lr = l & 15, lh4 = l >> 4;

  // ---- Ws fragments -> registers (rank's 32 rows, wave's K-quarter) ----
  s16x8 bhi[2][8], blo[2][8];
#pragma unroll
  for (int nt = 0; nt < 2; ++nt) {
#pragma unroll
    for (int c = 0; c < 8; ++c) {
      const int e = rank * 32 + nt * 16 + lr;
      const int k = kq * 256 + c * 32 + lh4 * 8;
      const float* src = Ws + (size_t)e * DIM + k;
      f32x4 v0 = *(const f32x4*)src;
      f32x4 v1 = *(const f32x4*)(src + 4);
      s16x8 vh, vl;
#pragma unroll
      for (int j = 0; j < 4; ++j) {
        unsigned short hb = f2bf(v0[j]);
        vh[j] = (short)hb;
        vl[j] = (short)f2bf(v0[j] - bf2f(hb));
        unsigned short hb2 = f2bf(v1[j]);
        vh[4 + j] = (short)hb2;
        vl[4 + j] = (short)f2bf(v1[j] - bf2f(hb2));
      }
      bhi[nt][c] = vh; blo[nt][c] = vl;
    }
  }

  // ---- wave0 epilogue state: lane handles (batch=lh4, e=egl..egl+1) ----
  float hold0 = 0.f, hold1 = 0.f;
  float2 bs2 = {0.f, 0.f};
  size_t gpi = 0;
  int bgl = 0, egl = 0;
  if (tid < 64) {
    bgl = g * 4 + lh4;
    egl = rank * 32 + lr * 2;
    bs2 = *(const float2*)&bs[egl];
    gpi = ((size_t)bgl * SEQ) * DIM + egl;
  }
  float2 gA = {0, 0}, pA = {0, 0}, gB = {0, 0}, pB = {0, 0};
  if (tid < 64) { gA = *(const float2*)&G[gpi]; pA = *(const float2*)&out[gpi]; }

  // per-lane h-load base (element units); batch row = lr (<4 valid)
  const int lane_off = lr * 1024 + kq * 256 + lh4 * 8;
  const int* fp = flags + ((g << 5) + (kq << 3) + (l & 7)) * 16;
  int* myflag = flags + ((g << 5) + rank) * 16;

  auto body = [&](int t, float2& gc, float2& pc, float2& gn, float2& pn) {
    // ---- poll own 8 producers (>= t) ----
    {
      int v;
      do { v = cload4(fp); } while (__any(v < t));
    }
    __builtin_amdgcn_sched_barrier(0);

    // ---- load h_t fragments (sc0sc1, coalesced) ----
    const unsigned short* Hh =
        h_hi + (size_t)(((t & 1) * 8 + g) * 4) * 1024 + lane_off;
    const unsigned short* Hl =
        h_lo + (size_t)(((t & 1) * 8 + g) * 4) * 1024 + lane_off;
    s16x8 ah[8], al[8];
    if (lr < 4) {
      HL8(ah, Hh);
      HL8(al, Hl);
    } else {
      s16x8 z8 = {0, 0, 0, 0, 0, 0, 0, 0};
#pragma unroll
      for (int c = 0; c < 8; ++c) { ah[c] = z8; al[c] = z8; }
    }
    asm volatile("s_waitcnt vmcnt(0)" ::: "memory");
    __builtin_amdgcn_sched_barrier(0);

    // ---- prefetch g,p for t+1 (plain cached loads; resolve during MFMA) ----
    if (tid < 64) {
      const size_t gpn = gpi + ((t + 1 < SEQ) ? DIM : 0);
      gn = *(const float2*)&G[gpn];
      pn = *(const float2*)&out[gpn];
    }

    // ---- 3-term split-bf16 MFMA (A rows = batches, 4 valid) ----
    f32x4 z = {0.f, 0.f, 0.f, 0.f};
    f32x4 aA[2], aB[2], aC[2];
#pragma unroll
    for (int nt = 0; nt < 2; ++nt) { aA[nt] = z; aB[nt] = z; aC[nt] = z; }
#pragma unroll
    for (int c = 0; c < 8; ++c) {
#pragma unroll
      for (int nt = 0; nt < 2; ++nt) {
        aA[nt] = __builtin_amdgcn_mfma_f32_16x16x32_bf16(ah[c], bhi[nt][c], aA[nt], 0, 0, 0);
        aB[nt] = __builtin_amdgcn_mfma_f32_16x16x32_bf16(al[c], bhi[nt][c], aB[nt], 0, 0, 0);
        aC[nt] = __builtin_amdgcn_mfma_f32_16x16x32_bf16(ah[c], blo[nt][c], aC[nt], 0, 0, 0);
      }
    }

    // ---- partials to LDS (valid batches: lanes lh4==0, regs i=0..3) ----
    if (lh4 == 0) {
#pragma unroll
      for (int nt = 0; nt < 2; ++nt) {
        f32x4 v = aA[nt] + aB[nt] + aC[nt];
#pragma unroll
        for (int i = 0; i < 4; ++i)
          part[(t & 1) * 512 + kq * 128 + i * 32 + nt * 16 + lr] = v[i];
      }
    }
    asm volatile("s_waitcnt lgkmcnt(0)" ::: "memory");
    __builtin_amdgcn_s_barrier();
    __builtin_amdgcn_sched_barrier(0);

    // ---- wave0: K-reduce + epilogue + publish ----
    if (tid < 64) {
      const int b = lh4, e2 = lr * 2;
      const float* pp = &part[(t & 1) * 512 + b * 32 + e2];
      float2 r0 = *(const float2*)&pp[0];
      float2 r1 = *(const float2*)&pp[128];
      float2 r2 = *(const float2*)&pp[256];
      float2 r3 = *(const float2*)&pp[384];
      const float s0 = r0.x + r1.x + r2.x + r3.x;
      const float s1 = r0.y + r1.y + r2.y + r3.y;
      const float mix0 = s0 + bs2.x + pc.x;
      const float mix1 = s1 + bs2.y + pc.y;
      const float h0 = gc.x * mix0 + (1.f - gc.x) * hold0;
      const float h1 = gc.y * mix1 + (1.f - gc.y) * hold1;
      hold0 = h0; hold1 = h1;

      const unsigned short hb0 = f2bf(h0), hb1 = f2bf(h1);
      const unsigned short lb0 = f2bf(h0 - bf2f(hb0)), lb1 = f2bf(h1 - bf2f(hb1));
      const size_t hoff =
          (size_t)((((t + 1) & 1) * 8 + g) * 4 + b) * 1024 + egl;
      cstore4u(h_hi + hoff, (unsigned)hb0 | ((unsigned)hb1 << 16));
      cstore4u(h_lo + hoff, (unsigned)lb0 | ((unsigned)lb1 << 16));
      asm volatile("s_waitcnt vmcnt(0)" ::: "memory");  // h visible before flag
      if (l == 0 && t < SEQ - 1) cstore4(myflag, t + 1);

      float2 ev; ev.x = h0; ev.y = h1;
      *(float2*)&out[gpi] = ev;  // emitted (overwrites consumed P slot)
      if (t == SEQ - 1)
        *(float2*)&out[BSD + (size_t)bgl * DIM + egl] = ev;
      gpi += ((t + 1 < SEQ) ? DIM : 0);
    }
  };

#pragma unroll 1
  for (int t = 0; t < SEQ; t += 2) {
    body(t, gA, pA, gB, pB);
    body(t + 1, gB, pB, gA, pA);
  }
}

// ---------------- launch ----------------
extern "C" void kernel_launch(void* const* d_in, const int* in_sizes, int n_in,
                              void* d_out, int out_size, void* d_ws, size_t ws_size,
                              hipStream_t stream) {
  (void)in_sizes; (void)n_in; (void)out_size; (void)ws_size;
  const float* x  = (const float*)d_in[0];
  const float* Wg = (const float*)d_in[1];
  const float* bg = (const float*)d_in[2];
  const float* Ws = (const float*)d_in[3];
  const float* bs = (const float*)d_in[4];
  const float* Wi = (const float*)d_in[5];
  const float* bi = (const float*)d_in[6];
  float* out = (float*)d_out;
  char* ws = (char*)d_ws;

  unsigned short* xh   = (unsigned short*)(ws);              // 64 MB
  unsigned short* xl   = (unsigned short*)(ws + 67108864);   // 64 MB
  unsigned short* wh   = (unsigned short*)(ws + 134217728);  // 4 MB (dead after gemm)
  unsigned short* wl   = (unsigned short*)(ws + 138412032);  // 4 MB (dead after gemm)
  float*          G    = (float*)(ws + 142606336);           // 128 MB
  unsigned short* h_hi = (unsigned short*)(ws + 276824064);  // 128 KB [2][8][4][1024]
  unsigned short* h_lo = (unsigned short*)(ws + 276955136);  // 128 KB
  int*            flags= (int*)(ws + 134217728);             // 16 KB (overlaps wh; init AFTER gemm)

  hipLaunchKernelGGL(split_x_kernel, dim3(4096), dim3(256), 0, stream,
                     x, xh, xl, (long)(BSD / 4));
  hipLaunchKernelGGL(split_w_kernel, dim3(2048), dim3(256), 0, stream, Wg, Wi, wh, wl);
  hipLaunchKernelGGL(gemm_gp_kernel, dim3(256, 16), dim3(256), 0, stream,
                     xh, xl, wh, wl, bg, bi, G, out);
  hipLaunchKernelGGL(init_kernel, dim3(64), dim3(256), 0, stream, h_hi, h_lo, flags);
  hipLaunchKernelGGL(recur_kernel, dim3(256), dim3(256), 0, stream,
                     Ws, bs, G, out, h_hi, h_lo, flags);
}